// Round 1
// baseline (199.529 us; speedup 1.0000x reference)
//
#include <hip/hip_runtime.h>

// Problem constants (from reference)
#define KSIZE   32
#define KSTRIDE 16
#define HK      4
#define HD      128
#define ROW     (HK * HD)                       // 512 floats per token
#define ROW4    (ROW / 4)                       // 128 float4 per token
#define BATCH   4
#define SEQLEN  16384
#define CHUNKS_PER_BATCH ((SEQLEN - KSIZE) / KSTRIDE + 1)   // 1023
#define TOTAL_CHUNKS     (BATCH * CHUNKS_PER_BATCH)         // 4092

// G chunks per block: block owning G consecutive chunks reads (G+1)*16 rows
// instead of G*32 (1.33x amplification at G=3; boundary half-windows shared
// with the neighbor block are recovered via same-XCD L2 with the swizzle).
#define G 3
#define BLOCKS_PER_BATCH (CHUNKS_PER_BATCH / G)             // 341
#define TOTAL_BLOCKS     (BATCH * BLOCKS_PER_BATCH)         // 1364
#define NXCD 8

// 512 threads: col = t&127 owns float4 column, q = t>>7 owns a 4-row quarter
// of each 16-row half-window. Raises occupancy from 10.7 to >=16 waves/CU
// (grid-limited before). Partials combined via 32 KiB LDS.
__global__ __launch_bounds__(512, 4)
void compress_k_fused(const float* __restrict__ k,
                      const int* __restrict__ cu_seqlens,
                      float* __restrict__ out,
                      float* __restrict__ tail) {
    // Bijective XCD-aware swizzle (m204 form; 1364 = 8*170 + 4, so the naive
    // (bid%8)*ceil form would be non-bijective). Consecutive logical blocks
    // (which share a 16-row half-window) land on the SAME XCD's L2.
    const int bid = blockIdx.x;
    const int xcd = bid % NXCD;
    const int sub = bid / NXCD;
    const int q8  = TOTAL_BLOCKS / NXCD;          // 170
    const int r8  = TOTAL_BLOCKS % NXCD;          // 4
    const int blk = (xcd < r8 ? xcd * (q8 + 1)
                              : r8 * (q8 + 1) + (xcd - r8) * q8) + sub;

    const int b   = blk / BLOCKS_PER_BATCH;
    const int cb  = blk - b * BLOCKS_PER_BATCH;   // block index within batch
    const int c0  = cb * G;                        // first chunk (within batch)

    const long start_row = (long)cu_seqlens[b] + (long)c0 * KSTRIDE;
    const float4* __restrict__ src = (const float4*)(k + start_row * ROW);

    const int t   = threadIdx.x;                  // 0..511
    const int col = t & (ROW4 - 1);               // float4 column 0..127
    const int q   = t >> 7;                       // row-quarter 0..3

    // Per-thread partial: 4 rows of each of the G+1 half-windows.
    float4 p[G + 1];
    #pragma unroll
    for (int j = 0; j <= G; ++j) p[j] = make_float4(0.f, 0.f, 0.f, 0.f);

    #pragma unroll
    for (int j = 0; j <= G; ++j) {
        #pragma unroll
        for (int r = 0; r < 4; ++r) {
            float4 v = src[(long)(j * KSTRIDE + q * 4 + r) * ROW4 + col];
            p[j].x += v.x; p[j].y += v.y; p[j].z += v.z; p[j].w += v.w;
        }
    }

    // Combine the 4 row-quarters through LDS.
    __shared__ float4 ls[G + 1][4][ROW4];         // 4*4*128*16B = 32 KiB
    #pragma unroll
    for (int j = 0; j <= G; ++j) ls[j][q][col] = p[j];
    __syncthreads();

    if (q < G) {
        const int g = q;                          // chunk within block
        float4 h = make_float4(0.f, 0.f, 0.f, 0.f);
        #pragma unroll
        for (int qq = 0; qq < 4; ++qq) {
            float4 a = ls[g][qq][col];
            float4 c = ls[g + 1][qq][col];
            h.x += a.x + c.x; h.y += a.y + c.y;
            h.z += a.z + c.z; h.w += a.w + c.w;
        }
        const float s = 1.0f / (float)KSIZE;
        h.x *= s; h.y *= s; h.z *= s; h.w *= s;
        const int chunk0 = b * CHUNKS_PER_BATCH + c0;
        ((float4*)(out + (long)(chunk0 + g) * ROW))[col] = h;
    }

    // Fused cu_comp tail write (fp32 representation in the flat out buffer).
    if (bid == 0 && t == 0) {
        int run = 0;
        tail[0] = 0.0f;
        #pragma unroll
        for (int i = 0; i < BATCH; ++i) {
            const int len = cu_seqlens[i + 1] - cu_seqlens[i];
            const int n = (len >= KSIZE) ? (len - KSIZE) / KSTRIDE + 1 : 0;
            run += n;
            tail[i + 1] = (float)run;
        }
    }
}

extern "C" void kernel_launch(void* const* d_in, const int* in_sizes, int n_in,
                              void* d_out, int out_size, void* d_ws, size_t ws_size,
                              hipStream_t stream) {
    const float* k          = (const float*)d_in[0];
    const int*   cu_seqlens = (const int*)d_in[1];
    float*       out        = (float*)d_out;
    float*       tail       = out + (long)TOTAL_CHUNKS * ROW;

    compress_k_fused<<<TOTAL_BLOCKS, 512, 0, stream>>>(k, cu_seqlens, out, tail);
}